// Round 11
// baseline (520.052 us; speedup 1.0000x reference)
//
#include <hip/hip_runtime.h>
#include <hip/hip_bf16.h>

#define TPB   256
#define NB    1024        // buckets: user >> 10 (1M users -> 128 KB table window)
#define HBLK  256         // histogram blocks
#define SBLK  1024        // scatter blocks
#define DBLK  2048        // main-kernel blocks

typedef float f2 __attribute__((ext_vector_type(2)));
static __device__ __forceinline__ f2 mk2(float a, float b) { f2 r; r.x = a; r.y = b; return r; }

// ws layout (byte offsets):
//   0       : W  float[1024]   weights repack (785 used)
//   4096    : hist   u32[NB]
//   8192    : cursor u32[NB]
//   16384   : su u32[n]   bucket-sorted user idx
//   +4n     : sm u32[n]   bucket-sorted movie idx
//   +8n     : se u32[n]   original element id

__global__ void prep_kernel(const float* __restrict__ w1, const float* __restrict__ b1,
                            const float* __restrict__ w2, const float* __restrict__ b2,
                            float* __restrict__ W, unsigned* __restrict__ hist) {
    int t = threadIdx.x;
    for (int i = t; i < 768; i += TPB) {
        int grp = i >> 8, r = i & 255, j = r >> 5, k = r & 31;
        W[i] = w1[j * 96 + grp * 32 + k];
    }
    if (t < 8) W[768 + t] = b1[t];
    if (t < 8) W[776 + t] = w2[t];
    if (t == 0) W[784]    = b2[0];
    for (int i = t; i < NB; i += TPB) hist[i] = 0u;
}

__global__ __launch_bounds__(TPB) void hist_kernel(
    const int* __restrict__ users, unsigned* __restrict__ hist, int n) {
    __shared__ unsigned lh[NB];
    for (int i = threadIdx.x; i < NB; i += TPB) lh[i] = 0u;
    __syncthreads();
    int stride = gridDim.x * TPB;
    for (int i = blockIdx.x * TPB + threadIdx.x; i < n; i += stride)
        atomicAdd(&lh[((unsigned)users[i]) >> 10], 1u);
    __syncthreads();
    for (int i = threadIdx.x; i < NB; i += TPB) {
        unsigned v = lh[i];
        if (v) atomicAdd(&hist[i], v);
    }
}

// one block of NB threads: cursor = exclusive_scan(hist)
__global__ void scan_kernel(const unsigned* __restrict__ hist, unsigned* __restrict__ cursor) {
    __shared__ unsigned s[NB];
    int t = threadIdx.x;
    unsigned mine = hist[t];
    s[t] = mine;
    __syncthreads();
    for (int off = 1; off < NB; off <<= 1) {
        unsigned v = (t >= off) ? s[t - off] : 0u;
        __syncthreads();
        s[t] += v;
        __syncthreads();
    }
    cursor[t] = s[t] - mine;   // exclusive base; scatter atomics bump from here
}

__global__ __launch_bounds__(TPB) void scatter_kernel(
    const int* __restrict__ users, const int* __restrict__ movies,
    unsigned* __restrict__ cursor,
    unsigned* __restrict__ su, unsigned* __restrict__ sm, unsigned* __restrict__ se, int n) {
    int stride = gridDim.x * TPB;
    for (int i = blockIdx.x * TPB + threadIdx.x; i < n; i += stride) {
        unsigned u = (unsigned)users[i];
        unsigned m = (unsigned)movies[i];
        unsigned p = atomicAdd(&cursor[u >> 10], 1u);
        su[p] = u; sm[p] = m; se[p] = (unsigned)i;
    }
}

// Round-10 cooperative compute (8 lanes per element, shfl_xor K-reduction),
// but indices arrive bucket-sorted -> user-row gathers are DRAM-page-local.
__global__ __launch_bounds__(TPB, 3) void mf_kernel(
    const unsigned* __restrict__ su, const unsigned* __restrict__ sm,
    const unsigned* __restrict__ se,
    const float4* __restrict__ uemb,   // fp32 [1e6][8] float4
    const float4* __restrict__ memb,   // fp32 [1e5][8]
    const float* __restrict__ W,
    float* __restrict__ out, int n) {

    const int t    = threadIdx.x;
    const int lane = t & 63;
    const int c    = lane & 7;       // k-chunk within the row
    const int g    = lane >> 3;      // element-group within the wave
    const int wid  = blockIdx.x * (TPB >> 6) + (t >> 6);
    const int nw   = DBLK * (TPB >> 6);

    float4 WAq[8], WBq[8], WCq[8];
#pragma unroll
    for (int j = 0; j < 8; ++j) {
        WAq[j] = *(const float4*)(W +       j * 32 + 4 * c);
        WBq[j] = *(const float4*)(W + 256 + j * 32 + 4 * c);
        WCq[j] = *(const float4*)(W + 512 + j * 32 + 4 * c);
    }
    float b1j[8], w2j[8];
#pragma unroll
    for (int j = 0; j < 8; ++j) { b1j[j] = W[768 + j]; w2j[j] = W[776 + j]; }
    const float b2 = W[784];

    const int n8 = (n + 7) >> 3;
    for (int o = wid; o < n8; o += nw) {
        int rec = o * 8 + g;
        int rc  = (rec < n) ? rec : (n - 1);
        unsigned ui  = su[rc];       // broadcast within the 8-lane group
        unsigned mi  = sm[rc];
        unsigned eid = se[rc];
        float4 u4 = uemb[(size_t)ui * 8 + c];   // 8 rows x 128 B per instruction
        float4 m4 = memb[(size_t)mi * 8 + c];

        f2 u01 = mk2(u4.x, u4.y), u23 = mk2(u4.z, u4.w);
        f2 m01 = mk2(m4.x, m4.y), m23 = mk2(m4.z, m4.w);
        f2 p01 = u01 * m01,       p23 = u23 * m23;

        float h[8];
#pragma unroll
        for (int j = 0; j < 8; ++j) {
            f2 a = mk2(0.0f, 0.0f);
            a = __builtin_elementwise_fma(p01, mk2(WAq[j].x, WAq[j].y), a);
            a = __builtin_elementwise_fma(p23, mk2(WAq[j].z, WAq[j].w), a);
            a = __builtin_elementwise_fma(u01, mk2(WBq[j].x, WBq[j].y), a);
            a = __builtin_elementwise_fma(u23, mk2(WBq[j].z, WBq[j].w), a);
            a = __builtin_elementwise_fma(m01, mk2(WCq[j].x, WCq[j].y), a);
            a = __builtin_elementwise_fma(m23, mk2(WCq[j].z, WCq[j].w), a);
            h[j] = a.x + a.y;
        }

#pragma unroll
        for (int j = 0; j < 8; ++j) h[j] += __shfl_xor(h[j], 1, 64);
#pragma unroll
        for (int j = 0; j < 8; ++j) h[j] += __shfl_xor(h[j], 2, 64);
#pragma unroll
        for (int j = 0; j < 8; ++j) h[j] += __shfl_xor(h[j], 4, 64);

        float z = b2;
#pragma unroll
        for (int j = 0; j < 8; ++j)
            z = fmaf(fmaxf(h[j] + b1j[j], 0.0f), w2j[j], z);

        float r = 1.0f / (1.0f + __expf(-z));
        if (c == 0 && rec < n) out[eid] = r;
    }
}

extern "C" void kernel_launch(void* const* d_in, const int* in_sizes, int n_in,
                              void* d_out, int out_size, void* d_ws, size_t ws_size,
                              hipStream_t stream) {
    const int* users   = (const int*)d_in[0];
    const int* movies  = (const int*)d_in[1];
    const float4* uemb = (const float4*)d_in[2];   // fp32 [1e6, 32]
    const float4* memb = (const float4*)d_in[3];   // fp32 [1e5, 32]
    const float* w1    = (const float*)d_in[4];    // fp32 [8, 96]
    const float* b1    = (const float*)d_in[5];    // fp32 [8]
    const float* w2    = (const float*)d_in[6];    // fp32 [1, 8]
    const float* b2    = (const float*)d_in[7];    // fp32 [1]
    float* out = (float*)d_out;

    int n = in_sizes[0];
    char* wsb = (char*)d_ws;
    float*    W      = (float*)wsb;
    unsigned* hist   = (unsigned*)(wsb + 4096);
    unsigned* cursor = (unsigned*)(wsb + 8192);
    unsigned* su     = (unsigned*)(wsb + 16384);
    unsigned* sm     = su + n;
    unsigned* se     = sm + n;

    prep_kernel   <<<1,    TPB, 0, stream>>>(w1, b1, w2, b2, W, hist);
    hist_kernel   <<<HBLK, TPB, 0, stream>>>(users, hist, n);
    scan_kernel   <<<1,    NB,  0, stream>>>(hist, cursor);
    scatter_kernel<<<SBLK, TPB, 0, stream>>>(users, movies, cursor, su, sm, se, n);
    mf_kernel     <<<DBLK, TPB, 0, stream>>>(su, sm, se, uemb, memb, W, out, n);
}